// Round 8
// baseline (627.547 us; speedup 1.0000x reference)
//
#include <hip/hip_runtime.h>
#include <hip/hip_bf16.h>

typedef unsigned short u16;
typedef unsigned int u32;
#define DI __device__ __forceinline__

typedef __attribute__((ext_vector_type(8))) short v8s;
typedef __attribute__((ext_vector_type(4))) float v4f;

constexpr int B_ = 8;
constexpr int V_ = 4096;   // 64*64
constexpr int C_ = 256;    // Cin = Cout
constexpr int F_ = 128;
constexpr int E_ = 256;
constexpr int KK_ = 49;    // 7x7
constexpr int PWS = 80;    // padded row stride (u16)
constexpr int PS  = 5600;  // padded plane stride (u16)
constexpr int SLICE = 524288;  // one k_tmp partial slice: 8*256*256 f32

// ---- ws layout (float indices). Total 10,655,744 fl = 42.6 MB ----
constexpr size_t OFF_XSUM   = 0;         // 2048
constexpr size_t OFF_CSUM   = 2048;      // 2048
constexpr size_t OFF_SPHI   = 4096;      // 1024
constexpr size_t OFF_A      = 5120;      // 1024
constexpr size_t OFF_T      = 6144;      // f32 tT[b][e][f]: 262144 (atomic);
                                         // REUSED by k_hd as csum partials [b][chunk][e]
constexpr size_t OFF_TMPT   = 268288;    // (unused now; kept for layout stability)
constexpr size_t ZERO_HEAD  = 792576;    // memset [0, here)
constexpr size_t OFF_TT16   = 792576;    // bf16 tT16[b][e][f]: 131072 fl
constexpr size_t OFF_T2T16  = 923648;    // bf16 tmp2T[b][c][e]: 262144 fl
constexpr size_t OFF_W2T16  = 1185792;   // bf16 w2T[co][c]: 32768 fl
constexpr size_t OFF_PHIT   = 1218560;   // bf16 phiT[b][f][v]: 2097152 fl
constexpr size_t OFF_XPT    = 3315712;   // bf16 xpadT: 5734400 fl; hmS16 overlays after gemm1
constexpr size_t XPT_FLOATS = 5734400;
constexpr size_t OFF_WMT    = 9050112;   // bf16 wmT[kk][e][c]: 1605632 fl

DI float bf2f(u16 u) {
    union { u32 i; float f; } v; v.i = ((u32)u) << 16; return v.f;
}
DI u16 f2bf(float f) {
    union { float f; u32 i; } v; v.f = f;
    u32 r = v.i + 0x7fff + ((v.i >> 16) & 1);
    return (u16)(r >> 16);
}

// ---- xsum[b][c] = sum_v x[b,v,c] ----
__global__ void k_xsum(const float* __restrict__ x, float* __restrict__ ws) {
    int b = blockIdx.x >> 5;
    int chunk = blockIdx.x & 31;
    int c = threadIdx.x;
    const float* xb = x + ((size_t)b * V_ + chunk * 128) * C_ + c;
    float s = 0.f;
    for (int v = 0; v < 128; ++v) s += xb[(size_t)v * C_];
    atomicAdd(&ws[OFF_XSUM + b * C_ + c], s);
}

// ---- a[b][f] = mean(x) @ w_a + b_a ----
__global__ void k_a(const float* __restrict__ w_a, const float* __restrict__ b_a,
                    float* __restrict__ ws) {
    int b = blockIdx.x, f = threadIdx.x;
    float acc = b_a[f];
    const float* xs = &ws[OFF_XSUM + b * C_];
    for (int c = 0; c < C_; ++c)
        acc += (xs[c] * (1.0f / 4096.0f)) * w_a[c * F_ + f];
    ws[OFF_A + b * F_ + f] = acc;
}

// ---- phiT[b][f][v] = bf16(x @ w_phi + b_phi), sphi ----
__global__ void k_phi(const float* __restrict__ x, const float* __restrict__ w_phi,
                      const float* __restrict__ b_phi, float* __restrict__ ws) {
    __shared__ float xsT[C_][8];
    int r0 = blockIdx.x * 8;
    int b = r0 >> 12;
    int v0 = r0 & 4095;
    int tid = threadIdx.x;
    const float* xb = x + (size_t)r0 * C_;
    for (int i = tid; i < 8 * C_; i += 128) xsT[i & 255][i >> 8] = xb[i];
    __syncthreads();
    int f = tid;
    float bp = b_phi[f];
    float acc[8];
#pragma unroll
    for (int r = 0; r < 8; ++r) acc[r] = bp;
    const float* wp = w_phi + f;
    for (int c = 0; c < C_; ++c) {
        float w = wp[c * F_];
        float4 xa = *(const float4*)&xsT[c][0];
        float4 xb4 = *(const float4*)&xsT[c][4];
        acc[0] += xa.x * w;  acc[1] += xa.y * w;  acc[2] += xa.z * w;  acc[3] += xa.w * w;
        acc[4] += xb4.x * w; acc[5] += xb4.y * w; acc[6] += xb4.z * w; acc[7] += xb4.w * w;
    }
    u16 pb[8];
    float ssum = 0.f;
#pragma unroll
    for (int r = 0; r < 8; ++r) { pb[r] = f2bf(acc[r]); ssum += acc[r]; }
    u16* phiT = (u16*)&ws[OFF_PHIT];
    uint4 q;
    q.x = (u32)pb[0] | ((u32)pb[1] << 16);
    q.y = (u32)pb[2] | ((u32)pb[3] << 16);
    q.z = (u32)pb[4] | ((u32)pb[5] << 16);
    q.w = (u32)pb[6] | ((u32)pb[7] << 16);
    *(uint4*)(phiT + ((size_t)(b * F_ + f)) * V_ + v0) = q;
    atomicAdd(&ws[OFF_SPHI + b * F_ + f], ssum);
}

// ---- xpadT[b][c][(h+3)*80 + (w+3)] = bf16(x), halo pre-zeroed ----
__global__ void k_padx(const float* __restrict__ x, float* __restrict__ ws) {
    __shared__ float tile[64][68];
    int b = blockIdx.x >> 6;
    int h = blockIdx.x & 63;
    int tid = threadIdx.x;
    u16* xpt = (u16*)&ws[OFF_XPT];
    for (int cc = 0; cc < 4; ++cc) {
        int c0 = cc * 64;
        int w = tid >> 2, q = tid & 3;
        const float* xr = x + ((size_t)(b * V_ + h * 64 + w)) * C_ + c0 + q * 16;
        float4 f0 = *(const float4*)(xr);
        float4 f1 = *(const float4*)(xr + 4);
        float4 f2 = *(const float4*)(xr + 8);
        float4 f3 = *(const float4*)(xr + 12);
        __syncthreads();
        *(float4*)&tile[w][q * 16]      = f0;
        *(float4*)&tile[w][q * 16 + 4]  = f1;
        *(float4*)&tile[w][q * 16 + 8]  = f2;
        *(float4*)&tile[w][q * 16 + 12] = f3;
        __syncthreads();
        int c = tid >> 2, j4 = tid & 3;
        u16* dst = xpt + ((size_t)(b * C_ + c0 + c)) * PS + (h + 3) * PWS + 3 + j4 * 16;
#pragma unroll
        for (int ww = 0; ww < 16; ++ww) dst[ww] = f2bf(tile[j4 * 16 + ww][c]);
    }
}

// ---- wmT[kk][e][c] = bf16(w_m[kk][c][e]) ----
__global__ void k_wmt(const float* __restrict__ w_m, float* __restrict__ ws) {
    int kk = blockIdx.x;
    int e = threadIdx.x;
    u16* wmt = (u16*)&ws[OFF_WMT];
    for (int c0 = 0; c0 < C_; c0 += 8) {
        u16 pk[8];
#pragma unroll
        for (int i = 0; i < 8; ++i)
            pk[i] = f2bf(w_m[((size_t)kk * C_ + c0 + i) * E_ + e]);
        uint4 q;
        q.x = (u32)pk[0] | ((u32)pk[1] << 16);
        q.y = (u32)pk[2] | ((u32)pk[3] << 16);
        q.z = (u32)pk[4] | ((u32)pk[5] << 16);
        q.w = (u32)pk[6] | ((u32)pk[7] << 16);
        *(uint4*)(wmt + ((size_t)(kk * E_ + e)) * C_ + c0) = q;
    }
}

// ---- w2T16[co][c] = bf16(w2[c][co]) ----
__global__ void k_w2t(const float* __restrict__ w2, float* __restrict__ ws) {
    int co = blockIdx.x, c = threadIdx.x;
    ((u16*)&ws[OFF_W2T16])[(size_t)co * C_ + c] = f2bf(w2[(size_t)c * C_ + co]);
}

// ---- gemm1 inner loop (static shift KX) ----
// R4-proven schedule (A+B LDS staged, dbuf, single __syncthreads) with the N
// dimension (c) split in half across blocks: B tile = 128 c rows, 8 MFMA per
// wave per chunk, LDS 40 KB -> 4 blocks/CU co-resident (8 waves/SIMD) so
// barrier stalls of one block overlap other blocks' MFMA (TLP, not ILP).
template <int KX>
DI void g1_loop(const u16* __restrict__ phiT_b, const u16* __restrict__ xpt_b,
                int ky, u16* lds_a, u16* lds_b, int tid, v4f acc[4][2]) {
    int wave = tid >> 6, lane = tid & 63, quad = lane >> 4, l15 = lane & 15;
    int mi2 = wave >> 2, ni2 = wave & 3;   // 2 (f) x 4 (c) wave grid over 128x128
    int fA = tid >> 2, vsA = (tid & 3) * 8;
    bool doB = tid < 256;                  // 128 B rows x 2 threads
    int cB = tid >> 1, sB = (tid & 1) * 16;
    const u16* bbase = xpt_b + (size_t)cB * PS + (size_t)ky * PWS + sB;
    constexpr int J0 = KX >> 1;
#pragma unroll 1
    for (int chunk = 0; chunk < 128; ++chunk) {
        int v0 = chunk * 32;
        int h = chunk >> 1, w0 = (chunk & 1) * 32;
        uint4 a4 = *(const uint4*)(phiT_b + (size_t)fA * V_ + v0 + vsA);
        u32 o[8];
        if (doB) {
            const u16* bp = bbase + h * PWS + w0;
            uint4 q0 = *(const uint4*)(bp);
            uint4 q1 = *(const uint4*)(bp + 8);
            u32 dw[12];
            dw[0] = q0.x; dw[1] = q0.y; dw[2] = q0.z; dw[3] = q0.w;
            dw[4] = q1.x; dw[5] = q1.y; dw[6] = q1.z; dw[7] = q1.w;
            if constexpr (KX >= 1) {
                uint4 q2 = *(const uint4*)(bp + 16);
                dw[8] = q2.x; dw[9] = q2.y; dw[10] = q2.z; dw[11] = q2.w;
            } else {
                dw[8] = dw[9] = dw[10] = dw[11] = 0;
            }
            if constexpr ((KX & 1) == 0) {
#pragma unroll
                for (int i = 0; i < 8; ++i) o[i] = dw[J0 + i];
            } else {
#pragma unroll
                for (int i = 0; i < 8; ++i) o[i] = (dw[J0 + i] >> 16) | (dw[J0 + i + 1] << 16);
            }
        }
        u16* la = lds_a + (chunk & 1) * (128 * 40);
        u16* lb = lds_b + (chunk & 1) * (128 * 40);
        *(uint4*)&la[fA * 40 + vsA] = a4;
        if (doB) {
            *(uint4*)&lb[cB * 40 + sB]     = (uint4){o[0], o[1], o[2], o[3]};
            *(uint4*)&lb[cB * 40 + sB + 8] = (uint4){o[4], o[5], o[6], o[7]};
        }
        __syncthreads();
        v8s afr[4], bfr[2];
#pragma unroll
        for (int ai = 0; ai < 4; ++ai)
            afr[ai] = *(const v8s*)&la[(mi2 * 64 + ai * 16 + l15) * 40 + quad * 8];
#pragma unroll
        for (int bi = 0; bi < 2; ++bi)
            bfr[bi] = *(const v8s*)&lb[(ni2 * 32 + bi * 16 + l15) * 40 + quad * 8];
#pragma unroll
        for (int ai = 0; ai < 4; ++ai)
#pragma unroll
            for (int bi = 0; bi < 2; ++bi)
                acc[ai][bi] = __builtin_amdgcn_mfma_f32_16x16x32_bf16(
                    afr[ai], bfr[bi], acc[ai][bi], 0, 0, 0);
    }
}

// ---- MFMA: G[b,kk][f][c] (bf16, in d_out) ----
// grid 784 = (kk*2+ch)*8 + b  -> XCD (wgid%8) == b: each XCD's L2 holds its
// batch's phiT (1MB) + xpadT (2.9MB) < 4MiB; both c-halves of a (b,kk) land
// on the same XCD so L2 reuse is intact.
__global__ __launch_bounds__(512, 8) void k_gemm1(const float* __restrict__ ws_c,
                                                  u16* __restrict__ G) {
    __shared__ u16 lds_a[2 * 128 * 40];   // 20 KB (double-buffered A tile)
    __shared__ u16 lds_b[2 * 128 * 40];   // 20 KB (double-buffered B half-tile)
    int b   = blockIdx.x & 7;
    int idx = blockIdx.x >> 3;
    int ch  = idx & 1;                    // c in [ch*128, ch*128+128)
    int kk  = idx >> 1;
    int ky = kk / 7, kx = kk % 7;
    int tid = threadIdx.x;
    int wave = tid >> 6, lane = tid & 63, quad = lane >> 4, l15 = lane & 15;
    int mi2 = wave >> 2, ni2 = wave & 3;
    const u16* phiT_b = (const u16*)&ws_c[OFF_PHIT] + (size_t)b * F_ * V_;
    const u16* xpt_b  = (const u16*)&ws_c[OFF_XPT] + (size_t)b * C_ * PS
                        + (size_t)ch * 128 * PS;
    v4f acc[4][2];
#pragma unroll
    for (int i = 0; i < 4; ++i)
#pragma unroll
        for (int j = 0; j < 2; ++j) acc[i][j] = (v4f){0.f, 0.f, 0.f, 0.f};
    switch (kx) {
        case 0: g1_loop<0>(phiT_b, xpt_b, ky, lds_a, lds_b, tid, acc); break;
        case 1: g1_loop<1>(phiT_b, xpt_b, ky, lds_a, lds_b, tid, acc); break;
        case 2: g1_loop<2>(phiT_b, xpt_b, ky, lds_a, lds_b, tid, acc); break;
        case 3: g1_loop<3>(phiT_b, xpt_b, ky, lds_a, lds_b, tid, acc); break;
        case 4: g1_loop<4>(phiT_b, xpt_b, ky, lds_a, lds_b, tid, acc); break;
        case 5: g1_loop<5>(phiT_b, xpt_b, ky, lds_a, lds_b, tid, acc); break;
        case 6: g1_loop<6>(phiT_b, xpt_b, ky, lds_a, lds_b, tid, acc); break;
    }
    u16* Gb = G + ((size_t)(b * KK_ + kk)) * F_ * C_;
#pragma unroll
    for (int ai = 0; ai < 4; ++ai)
#pragma unroll
        for (int bi = 0; bi < 2; ++bi) {
            int c = ch * 128 + ni2 * 32 + bi * 16 + l15;
#pragma unroll
            for (int r = 0; r < 4; ++r) {
                int f = mi2 * 64 + ai * 16 + quad * 4 + r;
                Gb[(size_t)f * C_ + c] = f2bf(acc[ai][bi][r]);
            }
        }
}

// ---- MFMA: tT[b][e][f] += G @ wmT (atomic f32) ----
__global__ void k_gemm2(const u16* __restrict__ G, float* __restrict__ ws) {
    int blk = blockIdx.x;
    int kg = blk % 7; blk /= 7;
    int ei = blk % 4; blk /= 4;
    int fi = blk % 2; int b = blk / 2;
    int tid = threadIdx.x;
    int wave = tid >> 6, lane = tid & 63, quad = lane >> 4, l15 = lane & 15;
    int fbase = fi * 64 + wave * 16;
    int ebase = ei * 64;
    const u16* wmt = (const u16*)&ws[OFF_WMT];
    const u16* Gb = G + (size_t)b * KK_ * F_ * C_;
    v4f acc[4];
#pragma unroll
    for (int i = 0; i < 4; ++i) acc[i] = (v4f){0.f, 0.f, 0.f, 0.f};
    for (int kk = kg * 7; kk < kg * 7 + 7; ++kk) {
        const u16* Ga = Gb + ((size_t)kk * F_ + fbase + l15) * C_;
        const u16* Wb = wmt + ((size_t)kk * E_ + ebase + l15) * C_;
#pragma unroll 2
        for (int cs = 0; cs < 8; ++cs) {
            v8s af = *(const v8s*)(Ga + cs * 32 + quad * 8);
#pragma unroll
            for (int nt = 0; nt < 4; ++nt) {
                v8s bf = *(const v8s*)(Wb + (size_t)nt * 16 * C_ + cs * 32 + quad * 8);
                acc[nt] = __builtin_amdgcn_mfma_f32_16x16x32_bf16(af, bf, acc[nt], 0, 0, 0);
            }
        }
    }
#pragma unroll
    for (int nt = 0; nt < 4; ++nt)
#pragma unroll
        for (int r = 0; r < 4; ++r) {
            int e = ebase + nt * 16 + l15;
            int f = fbase + quad * 4 + r;
            atomicAdd(&ws[OFF_T + ((size_t)(b * E_ + e)) * F_ + f], acc[nt][r]);
        }
}

// ---- tT16[b][e][f] = bf16( a[b,f] * (tT + sphi[b,f]*b_m[e]) ) ----
__global__ void k_tfix(const float* __restrict__ b_m, float* __restrict__ ws) {
    int b = blockIdx.x >> 8, e = blockIdx.x & 255, f = threadIdx.x;
    float av = ws[OFF_A + b * F_ + f];
    float sp = ws[OFF_SPHI + b * F_ + f];
    float t = av * (ws[OFF_T + ((size_t)(b * E_ + e)) * F_ + f] + sp * b_m[e]);
    ((u16*)&ws[OFF_TT16])[((size_t)(b * E_ + e)) * F_ + f] = f2bf(t);
}

// ---- MFMA: hmS16[v][e] = bf16(rsD[v]*|phi@t|), csum partials (NO atomics) ----
__global__ void k_hd(float* __restrict__ ws) {
    __shared__ u16 phiL[64 * 136];
    __shared__ float cspart[4][E_];       // per-wave column-sum partials
    int b = blockIdx.x >> 6;
    int chunkIdx = blockIdx.x & 63;
    int v0 = chunkIdx * 64;
    int tid = threadIdx.x;
    // stage phi[v][f] from phiT[f][v]
    {
        int f = tid & 127, seg = (tid >> 7) * 32;
        const u16* src = (const u16*)&ws[OFF_PHIT] + ((size_t)(b * F_ + f)) * V_ + v0 + seg;
        uint4 q0 = *(const uint4*)(src);
        uint4 q1 = *(const uint4*)(src + 8);
        uint4 q2 = *(const uint4*)(src + 16);
        uint4 q3 = *(const uint4*)(src + 24);
        u32 dw[16] = {q0.x, q0.y, q0.z, q0.w, q1.x, q1.y, q1.z, q1.w,
                      q2.x, q2.y, q2.z, q2.w, q3.x, q3.y, q3.z, q3.w};
#pragma unroll
        for (int j = 0; j < 16; ++j) {
            phiL[(seg + 2 * j) * 136 + f]     = (u16)(dw[j] & 0xffff);
            phiL[(seg + 2 * j + 1) * 136 + f] = (u16)(dw[j] >> 16);
        }
    }
    __syncthreads();
    int wave = tid >> 6, lane = tid & 63, quad = lane >> 4, l15 = lane & 15;
    const u16* tt = (const u16*)&ws[OFF_TT16] + (size_t)b * E_ * F_;
    v4f acc[16];
#pragma unroll
    for (int i = 0; i < 16; ++i) acc[i] = (v4f){0.f, 0.f, 0.f, 0.f};
#pragma unroll
    for (int kc = 0; kc < 4; ++kc) {
        v8s af = *(const v8s*)&phiL[(wave * 16 + l15) * 136 + kc * 32 + quad * 8];
#pragma unroll
        for (int nt = 0; nt < 16; ++nt) {
            v8s bf = *(const v8s*)(tt + (size_t)(nt * 16 + l15) * F_ + kc * 32 + quad * 8);
            acc[nt] = __builtin_amdgcn_mfma_f32_16x16x32_bf16(af, bf, acc[nt], 0, 0, 0);
        }
    }
#pragma unroll
    for (int nt = 0; nt < 16; ++nt)
#pragma unroll
        for (int r = 0; r < 4; ++r) acc[nt][r] = fabsf(acc[nt][r]);
    // row sums over e (256) -> rsD
    v4f rs = acc[0];
#pragma unroll
    for (int nt = 1; nt < 16; ++nt) rs += acc[nt];
#pragma unroll
    for (int m = 1; m < 16; m <<= 1) {
#pragma unroll
        for (int r = 0; r < 4; ++r) rs[r] += __shfl_xor(rs[r], m, 64);
    }
    float rsd[4];
#pragma unroll
    for (int r = 0; r < 4; ++r) rsd[r] = rsqrtf(rs[r]);
    // col sums (unscaled): quad-reduce in-wave -> per-wave LDS partial
#pragma unroll
    for (int nt = 0; nt < 16; ++nt) {
        float cs = acc[nt][0] + acc[nt][1] + acc[nt][2] + acc[nt][3];
        cs += __shfl_xor(cs, 16, 64);
        cs += __shfl_xor(cs, 32, 64);
        if (quad == 0) cspart[wave][nt * 16 + l15] = cs;
    }
    // store hmS16 = rsD*H
    u16* hm = (u16*)&ws[OFF_XPT];
#pragma unroll
    for (int nt = 0; nt < 16; ++nt)
#pragma unroll
        for (int r = 0; r < 4; ++r) {
            int v = v0 + wave * 16 + quad * 4 + r;
            hm[((size_t)(b * V_ + v)) * E_ + nt * 16 + l15] = f2bf(acc[nt][r] * rsd[r]);
        }
    __syncthreads();
    // cross-wave reduce + one coalesced plain store per thread
    {
        int e = tid;
        float s = cspart[0][e] + cspart[1][e] + cspart[2][e] + cspart[3][e];
        ws[OFF_T + ((size_t)(b * 64 + chunkIdx)) * E_ + e] = s;
    }
}

// ---- csum[b][e] = sum_chunk csp[b][chunk][e] ----
__global__ void k_csum(float* __restrict__ ws) {
    int b = blockIdx.x, e = threadIdx.x;
    const float* p = &ws[OFF_T + (size_t)b * 64 * E_ + e];
    float s = 0.f;
    for (int i = 0; i < 64; ++i) s += p[(size_t)i * E_];
    ws[OFF_CSUM + b * E_ + e] = s;
}

// ---- MFMA: tmp partials[vs][b][c][e] = sum_{v in slice} xT[c][v]*hmS^T[e][v] ----
// NO atomics: each of the 16 v-slices writes its own 2MB slice into d_out
// (dead between k_gemm2 and k_out; 16 x 2MB = 33.55MB = exactly out_size).
__global__ __launch_bounds__(512, 2) void k_tmp(const float* __restrict__ x,
                                                float* __restrict__ ws,
                                                float* __restrict__ part) {
    __shared__ u16 xT[256 * 40];
    __shared__ u16 hT[128 * 40];
    int blk = blockIdx.x;
    int eh = blk & 1; blk >>= 1;
    int vs = blk & 15; int b = blk >> 4;
    int v0b = vs * 256;
    int tid = threadIdx.x;
    int wave = tid >> 6, lane = tid & 63, quad = lane >> 4, l15 = lane & 15;
    int m0 = wave * 32;
    const u16* hmS = (const u16*)&ws[OFF_XPT];
    v4f acc[2][8];
#pragma unroll
    for (int i = 0; i < 2; ++i)
#pragma unroll
        for (int j = 0; j < 8; ++j) acc[i][j] = (v4f){0.f, 0.f, 0.f, 0.f};
    int sv = tid & 31, sg = tid >> 5;   // staging roles
#pragma unroll 1
    for (int ch = 0; ch < 8; ++ch) {
        int vbase = v0b + ch * 32;
        // load x row (16 f32) and hm row (8 u16) into regs
        const float* xr = x + ((size_t)(b * V_ + vbase + sv)) * C_ + sg * 16;
        float4 xf0 = *(const float4*)(xr);
        float4 xf1 = *(const float4*)(xr + 4);
        float4 xf2 = *(const float4*)(xr + 8);
        float4 xf3 = *(const float4*)(xr + 12);
        const u16* hr = hmS + ((size_t)(b * V_ + vbase + sv)) * E_ + eh * 128 + sg * 8;
        uint4 hq = *(const uint4*)hr;
        u16 hp[8] = {(u16)(hq.x & 0xffff), (u16)(hq.x >> 16), (u16)(hq.y & 0xffff),
                     (u16)(hq.y >> 16), (u16)(hq.z & 0xffff), (u16)(hq.z >> 16),
                     (u16)(hq.w & 0xffff), (u16)(hq.w >> 16)};
        float xv[16] = {xf0.x, xf0.y, xf0.z, xf0.w, xf1.x, xf1.y, xf1.z, xf1.w,
                        xf2.x, xf2.y, xf2.z, xf2.w, xf3.x, xf3.y, xf3.z, xf3.w};
        __syncthreads();
#pragma unroll
        for (int i = 0; i < 16; ++i) xT[(sg * 16 + i) * 40 + sv] = f2bf(xv[i]);
#pragma unroll
        for (int i = 0; i < 8; ++i) hT[(sg * 8 + i) * 40 + sv] = hp[i];
        __syncthreads();
        v8s a0 = *(const v8s*)&xT[(m0 + l15) * 40 + quad * 8];
        v8s a1 = *(const v8s*)&xT[(m0 + 16 + l15) * 40 + quad * 8];
#pragma unroll
        for (int nt = 0; nt < 8; ++nt) {
            v8s bf = *(const v8s*)&hT[(nt * 16 + l15) * 40 + quad * 8];
            acc[0][nt] = __builtin_amdgcn_mfma_f32_16x16x32_bf16(a0, bf, acc[0][nt], 0, 0, 0);
            acc[1][nt] = __builtin_amdgcn_mfma_f32_16x16x32_bf16(a1, bf, acc[1][nt], 0, 0, 0);
        }
    }
    float* po = part + (size_t)vs * SLICE;
#pragma unroll
    for (int mt = 0; mt < 2; ++mt)
#pragma unroll
        for (int nt = 0; nt < 8; ++nt)
#pragma unroll
            for (int r = 0; r < 4; ++r) {
                int c = m0 + mt * 16 + quad * 4 + r;
                int e = eh * 128 + nt * 16 + l15;
                po[((size_t)(b * C_ + c)) * E_ + e] = acc[mt][nt][r];
            }
}

// ---- tmp2T16[c][e] = bf16( (sum_s part[s][c][e]) / csum[e] ) ----
__global__ void k_t2fix(const float* __restrict__ part, float* __restrict__ ws) {
    int b = blockIdx.x >> 8, c = blockIdx.x & 255, e = threadIdx.x;
    float binv = 1.0f / ws[OFF_CSUM + b * E_ + e];
    size_t idx = ((size_t)(b * C_ + c)) * E_ + e;
    float tv = 0.f;
#pragma unroll
    for (int s = 0; s < 16; ++s) tv += part[(size_t)s * SLICE + idx];
    ((u16*)&ws[OFF_T2T16])[idx] = f2bf(tv * binv);
}

// ---- MFMA fused: out = (x - hmS16 @ tmp2T16) @ W2 + b2 ----
__global__ __launch_bounds__(256, 2) void k_out(const float* __restrict__ x,
                                                const float* __restrict__ b2,
                                                const float* __restrict__ ws,
                                                float* __restrict__ io) {
    __shared__ u16 dL[64 * 264];
    int b = blockIdx.x >> 6;
    int v0 = (blockIdx.x & 63) * 64;
    int tid = threadIdx.x;
    int wave = tid >> 6, lane = tid & 63, quad = lane >> 4, l15 = lane & 15;
    const u16* hm = (const u16*)&ws[OFF_XPT] + ((size_t)(b * V_ + v0 + wave * 16 + l15)) * E_;
    const u16* t2 = (const u16*)&ws[OFF_T2T16] + (size_t)b * C_ * E_;
    v4f acc[16];
#pragma unroll
    for (int i = 0; i < 16; ++i) acc[i] = (v4f){0.f, 0.f, 0.f, 0.f};
#pragma unroll 2
    for (int kc = 0; kc < 8; ++kc) {
        v8s af = *(const v8s*)(hm + kc * 32 + quad * 8);
#pragma unroll
        for (int nt = 0; nt < 16; ++nt) {
            v8s bf = *(const v8s*)(t2 + (size_t)(nt * 16 + l15) * E_ + kc * 32 + quad * 8);
            acc[nt] = __builtin_amdgcn_mfma_f32_16x16x32_bf16(af, bf, acc[nt], 0, 0, 0);
        }
    }
#pragma unroll
    for (int nt = 0; nt < 16; ++nt)
#pragma unroll
        for (int r = 0; r < 4; ++r) {
            int v = wave * 16 + quad * 4 + r;
            int c = nt * 16 + l15;
            float xv = x[((size_t)(b * V_ + v0 + v)) * C_ + c];
            dL[v * 264 + c] = f2bf(xv - acc[nt][r]);
        }
    __syncthreads();
    const u16* w2t = (const u16*)&ws[OFF_W2T16];
    v4f acc2[16];
#pragma unroll
    for (int i = 0; i < 16; ++i) acc2[i] = (v4f){0.f, 0.f, 0.f, 0.f};
#pragma unroll 2
    for (int kc = 0; kc < 8; ++kc) {
        v8s af = *(const v8s*)&dL[(wave * 16 + l15) * 264 + kc * 32 + quad * 8];
#pragma unroll
        for (int nt = 0; nt < 16; ++nt) {
            v8s bf = *(const v8s*)(w2t + (size_t)(nt * 16 + l15) * C_ + kc * 32 + quad * 8);
            acc2[nt] = __builtin_amdgcn_mfma_f32_16x16x32_bf16(af, bf, acc2[nt], 0, 0, 0);
        }
    }
#pragma unroll
    for (int nt = 0; nt < 16; ++nt)
#pragma unroll
        for (int r = 0; r < 4; ++r) {
            int v = wave * 16 + quad * 4 + r;
            int co = nt * 16 + l15;
            io[((size_t)(b * V_ + v0 + v)) * C_ + co] = acc2[nt][r] + b2[co];
        }
}

extern "C" void kernel_launch(void* const* d_in, const int* in_sizes, int n_in,
                              void* d_out, int out_size, void* d_ws, size_t ws_size,
                              hipStream_t stream) {
    const float* x     = (const float*)d_in[0];
    const float* w_phi = (const float*)d_in[1];
    const float* b_phi = (const float*)d_in[2];
    const float* w_a   = (const float*)d_in[3];
    const float* b_a   = (const float*)d_in[4];
    const float* w_m   = (const float*)d_in[5];
    const float* b_m   = (const float*)d_in[6];
    const float* w2    = (const float*)d_in[7];
    const float* b2    = (const float*)d_in[8];
    float* ws = (float*)d_ws;
    float* io = (float*)d_out;

    hipMemsetAsync(ws, 0, ZERO_HEAD * sizeof(float), stream);
    hipMemsetAsync(ws + OFF_XPT, 0, XPT_FLOATS * sizeof(float), stream);
    k_xsum<<<dim3(256), dim3(256), 0, stream>>>(x, ws);
    k_a<<<dim3(8), dim3(128), 0, stream>>>(w_a, b_a, ws);
    k_phi<<<dim3(4096), dim3(128), 0, stream>>>(x, w_phi, b_phi, ws);
    k_padx<<<dim3(512), dim3(256), 0, stream>>>(x, ws);
    k_wmt<<<dim3(49), dim3(256), 0, stream>>>(w_m, ws);
    k_w2t<<<dim3(256), dim3(256), 0, stream>>>(w2, ws);
    k_gemm1<<<dim3(784), dim3(512), 0, stream>>>(ws, (u16*)d_out);
    k_gemm2<<<dim3(448), dim3(256), 0, stream>>>((const u16*)d_out, ws);
    k_tfix<<<dim3(2048), dim3(128), 0, stream>>>(b_m, ws);
    k_hd<<<dim3(512), dim3(256), 0, stream>>>(ws);
    k_csum<<<dim3(8), dim3(256), 0, stream>>>(ws);
    k_tmp<<<dim3(256), dim3(512), 0, stream>>>(x, ws, (float*)d_out);
    k_t2fix<<<dim3(2048), dim3(256), 0, stream>>>((const float*)d_out, ws);
    k_out<<<dim3(512), dim3(256), 0, stream>>>(x, b2, ws, io);
}

// Round 9
// 570.289 us; speedup vs baseline: 1.1004x; 1.1004x over previous
//
#include <hip/hip_runtime.h>
#include <hip/hip_bf16.h>

typedef unsigned short u16;
typedef unsigned int u32;
#define DI __device__ __forceinline__

typedef __attribute__((ext_vector_type(8))) short v8s;
typedef __attribute__((ext_vector_type(4))) float v4f;

constexpr int B_ = 8;
constexpr int V_ = 4096;   // 64*64
constexpr int C_ = 256;    // Cin = Cout
constexpr int F_ = 128;
constexpr int E_ = 256;
constexpr int KK_ = 49;    // 7x7
constexpr int PWS = 80;    // padded row stride (u16)
constexpr int PS  = 5600;  // padded plane stride (u16)
constexpr int SLICE = 524288;  // one k_tmp partial slice: 8*256*256 f32

// ---- ws layout (float indices). Total 10,655,744 fl = 42.6 MB ----
constexpr size_t OFF_XSUM   = 0;         // 2048
constexpr size_t OFF_CSUM   = 2048;      // 2048
constexpr size_t OFF_SPHI   = 4096;      // 1024
constexpr size_t OFF_A      = 5120;      // 1024
constexpr size_t OFF_T      = 6144;      // f32 tT[b][e][f]: 262144 (atomic);
                                         // REUSED by k_hd as csum partials [b][chunk][e]
constexpr size_t OFF_TMPT   = 268288;    // (unused now; kept for layout stability)
constexpr size_t ZERO_HEAD  = 792576;    // memset [0, here)
constexpr size_t OFF_TT16   = 792576;    // bf16 tT16[b][e][f]: 131072 fl
constexpr size_t OFF_T2T16  = 923648;    // bf16 tmp2T[b][c][e]: 262144 fl
constexpr size_t OFF_W2T16  = 1185792;   // bf16 w2T[co][c]: 32768 fl
constexpr size_t OFF_PHIT   = 1218560;   // bf16 phiT[b][f][v]: 2097152 fl
constexpr size_t OFF_XPT    = 3315712;   // bf16 xpadT: 5734400 fl; hmS16 overlays after gemm1
constexpr size_t XPT_FLOATS = 5734400;
constexpr size_t OFF_WMT    = 9050112;   // bf16 wmT[kk][e][c]: 1605632 fl

DI float bf2f(u16 u) {
    union { u32 i; float f; } v; v.i = ((u32)u) << 16; return v.f;
}
DI u16 f2bf(float f) {
    union { float f; u32 i; } v; v.f = f;
    u32 r = v.i + 0x7fff + ((v.i >> 16) & 1);
    return (u16)(r >> 16);
}

// ---- xsum[b][c] = sum_v x[b,v,c] ----
__global__ void k_xsum(const float* __restrict__ x, float* __restrict__ ws) {
    int b = blockIdx.x >> 5;
    int chunk = blockIdx.x & 31;
    int c = threadIdx.x;
    const float* xb = x + ((size_t)b * V_ + chunk * 128) * C_ + c;
    float s = 0.f;
    for (int v = 0; v < 128; ++v) s += xb[(size_t)v * C_];
    atomicAdd(&ws[OFF_XSUM + b * C_ + c], s);
}

// ---- a[b][f] = mean(x) @ w_a + b_a ----
__global__ void k_a(const float* __restrict__ w_a, const float* __restrict__ b_a,
                    float* __restrict__ ws) {
    int b = blockIdx.x, f = threadIdx.x;
    float acc = b_a[f];
    const float* xs = &ws[OFF_XSUM + b * C_];
    for (int c = 0; c < C_; ++c)
        acc += (xs[c] * (1.0f / 4096.0f)) * w_a[c * F_ + f];
    ws[OFF_A + b * F_ + f] = acc;
}

// ---- phiT[b][f][v] = bf16(x @ w_phi + b_phi), sphi ----
__global__ void k_phi(const float* __restrict__ x, const float* __restrict__ w_phi,
                      const float* __restrict__ b_phi, float* __restrict__ ws) {
    __shared__ float xsT[C_][8];
    int r0 = blockIdx.x * 8;
    int b = r0 >> 12;
    int v0 = r0 & 4095;
    int tid = threadIdx.x;
    const float* xb = x + (size_t)r0 * C_;
    for (int i = tid; i < 8 * C_; i += 128) xsT[i & 255][i >> 8] = xb[i];
    __syncthreads();
    int f = tid;
    float bp = b_phi[f];
    float acc[8];
#pragma unroll
    for (int r = 0; r < 8; ++r) acc[r] = bp;
    const float* wp = w_phi + f;
    for (int c = 0; c < C_; ++c) {
        float w = wp[c * F_];
        float4 xa = *(const float4*)&xsT[c][0];
        float4 xb4 = *(const float4*)&xsT[c][4];
        acc[0] += xa.x * w;  acc[1] += xa.y * w;  acc[2] += xa.z * w;  acc[3] += xa.w * w;
        acc[4] += xb4.x * w; acc[5] += xb4.y * w; acc[6] += xb4.z * w; acc[7] += xb4.w * w;
    }
    u16 pb[8];
    float ssum = 0.f;
#pragma unroll
    for (int r = 0; r < 8; ++r) { pb[r] = f2bf(acc[r]); ssum += acc[r]; }
    u16* phiT = (u16*)&ws[OFF_PHIT];
    uint4 q;
    q.x = (u32)pb[0] | ((u32)pb[1] << 16);
    q.y = (u32)pb[2] | ((u32)pb[3] << 16);
    q.z = (u32)pb[4] | ((u32)pb[5] << 16);
    q.w = (u32)pb[6] | ((u32)pb[7] << 16);
    *(uint4*)(phiT + ((size_t)(b * F_ + f)) * V_ + v0) = q;
    atomicAdd(&ws[OFF_SPHI + b * F_ + f], ssum);
}

// ---- xpadT[b][c][(h+3)*80 + (w+3)] = bf16(x), halo pre-zeroed ----
__global__ void k_padx(const float* __restrict__ x, float* __restrict__ ws) {
    __shared__ float tile[64][68];
    int b = blockIdx.x >> 6;
    int h = blockIdx.x & 63;
    int tid = threadIdx.x;
    u16* xpt = (u16*)&ws[OFF_XPT];
    for (int cc = 0; cc < 4; ++cc) {
        int c0 = cc * 64;
        int w = tid >> 2, q = tid & 3;
        const float* xr = x + ((size_t)(b * V_ + h * 64 + w)) * C_ + c0 + q * 16;
        float4 f0 = *(const float4*)(xr);
        float4 f1 = *(const float4*)(xr + 4);
        float4 f2 = *(const float4*)(xr + 8);
        float4 f3 = *(const float4*)(xr + 12);
        __syncthreads();
        *(float4*)&tile[w][q * 16]      = f0;
        *(float4*)&tile[w][q * 16 + 4]  = f1;
        *(float4*)&tile[w][q * 16 + 8]  = f2;
        *(float4*)&tile[w][q * 16 + 12] = f3;
        __syncthreads();
        int c = tid >> 2, j4 = tid & 3;
        u16* dst = xpt + ((size_t)(b * C_ + c0 + c)) * PS + (h + 3) * PWS + 3 + j4 * 16;
#pragma unroll
        for (int ww = 0; ww < 16; ++ww) dst[ww] = f2bf(tile[j4 * 16 + ww][c]);
    }
}

// ---- wmT[kk][e][c] = bf16(w_m[kk][c][e]) ----
__global__ void k_wmt(const float* __restrict__ w_m, float* __restrict__ ws) {
    int kk = blockIdx.x;
    int e = threadIdx.x;
    u16* wmt = (u16*)&ws[OFF_WMT];
    for (int c0 = 0; c0 < C_; c0 += 8) {
        u16 pk[8];
#pragma unroll
        for (int i = 0; i < 8; ++i)
            pk[i] = f2bf(w_m[((size_t)kk * C_ + c0 + i) * E_ + e]);
        uint4 q;
        q.x = (u32)pk[0] | ((u32)pk[1] << 16);
        q.y = (u32)pk[2] | ((u32)pk[3] << 16);
        q.z = (u32)pk[4] | ((u32)pk[5] << 16);
        q.w = (u32)pk[6] | ((u32)pk[7] << 16);
        *(uint4*)(wmt + ((size_t)(kk * E_ + e)) * C_ + c0) = q;
    }
}

// ---- w2T16[co][c] = bf16(w2[c][co]) ----
__global__ void k_w2t(const float* __restrict__ w2, float* __restrict__ ws) {
    int co = blockIdx.x, c = threadIdx.x;
    ((u16*)&ws[OFF_W2T16])[(size_t)co * C_ + c] = f2bf(w2[(size_t)c * C_ + co]);
}

// ---- gemm1 inner loop (static shift KX) ----
// R4/R7-proven schedule: A+B both staged through double-buffered LDS, single
// __syncthreads per chunk. Verified-best at 164 µs; all five structural
// deviations tried (direct-A, reg-prefetch, sw-pipeline, 256-thr, C-split)
// regressed. Do not touch without new counter evidence.
template <int KX>
DI void g1_loop(const u16* __restrict__ phiT_b, const u16* __restrict__ xpt_b,
                int ky, u16* lds_a, u16* lds_b, int tid, v4f acc[4][4]) {
    int wave = tid >> 6, lane = tid & 63, quad = lane >> 4, l15 = lane & 15;
    int mi2 = wave >> 2, ni2 = wave & 3;
    int fA = tid >> 2, vsA = (tid & 3) * 8;
    int cB = tid >> 1, sB = (tid & 1) * 16;
    const u16* bbase = xpt_b + (size_t)cB * PS + (size_t)ky * PWS + sB;
    constexpr int J0 = KX >> 1;
#pragma unroll 1
    for (int chunk = 0; chunk < 128; ++chunk) {
        int v0 = chunk * 32;
        int h = chunk >> 1, w0 = (chunk & 1) * 32;
        uint4 a4 = *(const uint4*)(phiT_b + (size_t)fA * V_ + v0 + vsA);
        const u16* bp = bbase + h * PWS + w0;
        uint4 q0 = *(const uint4*)(bp);
        uint4 q1 = *(const uint4*)(bp + 8);
        u32 dw[12];
        dw[0] = q0.x; dw[1] = q0.y; dw[2] = q0.z; dw[3] = q0.w;
        dw[4] = q1.x; dw[5] = q1.y; dw[6] = q1.z; dw[7] = q1.w;
        if constexpr (KX >= 1) {
            uint4 q2 = *(const uint4*)(bp + 16);
            dw[8] = q2.x; dw[9] = q2.y; dw[10] = q2.z; dw[11] = q2.w;
        } else {
            dw[8] = dw[9] = dw[10] = dw[11] = 0;
        }
        u32 o[8];
        if constexpr ((KX & 1) == 0) {
#pragma unroll
            for (int i = 0; i < 8; ++i) o[i] = dw[J0 + i];
        } else {
#pragma unroll
            for (int i = 0; i < 8; ++i) o[i] = (dw[J0 + i] >> 16) | (dw[J0 + i + 1] << 16);
        }
        u16* la = lds_a + (chunk & 1) * (128 * 40);
        u16* lb = lds_b + (chunk & 1) * (256 * 40);
        *(uint4*)&la[fA * 40 + vsA] = a4;
        *(uint4*)&lb[cB * 40 + sB]     = (uint4){o[0], o[1], o[2], o[3]};
        *(uint4*)&lb[cB * 40 + sB + 8] = (uint4){o[4], o[5], o[6], o[7]};
        __syncthreads();
        v8s afr[4], bfr[4];
#pragma unroll
        for (int ai = 0; ai < 4; ++ai)
            afr[ai] = *(const v8s*)&la[(mi2 * 64 + ai * 16 + l15) * 40 + quad * 8];
#pragma unroll
        for (int bi = 0; bi < 4; ++bi)
            bfr[bi] = *(const v8s*)&lb[(ni2 * 64 + bi * 16 + l15) * 40 + quad * 8];
#pragma unroll
        for (int ai = 0; ai < 4; ++ai)
#pragma unroll
            for (int bi = 0; bi < 4; ++bi)
                acc[ai][bi] = __builtin_amdgcn_mfma_f32_16x16x32_bf16(
                    afr[ai], bfr[bi], acc[ai][bi], 0, 0, 0);
    }
}

// ---- MFMA: G[b,kk][f][c] (bf16, in d_out) ----
// grid 392 = kk*8 + b  -> XCD (wgid%8) == b: each XCD's L2 holds exactly its
// batch's phiT (1MB) + xpadT (2.9MB) < 4MiB, so per-chunk loads are L2 hits.
__global__ __launch_bounds__(512, 2) void k_gemm1(const float* __restrict__ ws_c,
                                                  u16* __restrict__ G) {
    __shared__ u16 lds_a[2 * 128 * 40];   // 20 KB (double-buffered A tile)
    __shared__ u16 lds_b[2 * 256 * 40];   // 40 KB (double-buffered B tile)
    int b  = blockIdx.x & 7;
    int kk = blockIdx.x >> 3;
    int ky = kk / 7, kx = kk % 7;
    int tid = threadIdx.x;
    int wave = tid >> 6, lane = tid & 63, quad = lane >> 4, l15 = lane & 15;
    int mi2 = wave >> 2, ni2 = wave & 3;
    const u16* phiT_b = (const u16*)&ws_c[OFF_PHIT] + (size_t)b * F_ * V_;
    const u16* xpt_b  = (const u16*)&ws_c[OFF_XPT] + (size_t)b * C_ * PS;
    v4f acc[4][4];
#pragma unroll
    for (int i = 0; i < 4; ++i)
#pragma unroll
        for (int j = 0; j < 4; ++j) acc[i][j] = (v4f){0.f, 0.f, 0.f, 0.f};
    switch (kx) {
        case 0: g1_loop<0>(phiT_b, xpt_b, ky, lds_a, lds_b, tid, acc); break;
        case 1: g1_loop<1>(phiT_b, xpt_b, ky, lds_a, lds_b, tid, acc); break;
        case 2: g1_loop<2>(phiT_b, xpt_b, ky, lds_a, lds_b, tid, acc); break;
        case 3: g1_loop<3>(phiT_b, xpt_b, ky, lds_a, lds_b, tid, acc); break;
        case 4: g1_loop<4>(phiT_b, xpt_b, ky, lds_a, lds_b, tid, acc); break;
        case 5: g1_loop<5>(phiT_b, xpt_b, ky, lds_a, lds_b, tid, acc); break;
        case 6: g1_loop<6>(phiT_b, xpt_b, ky, lds_a, lds_b, tid, acc); break;
    }
    u16* Gb = G + ((size_t)(b * KK_ + kk)) * F_ * C_;
#pragma unroll
    for (int ai = 0; ai < 4; ++ai)
#pragma unroll
        for (int bi = 0; bi < 4; ++bi) {
            int c = ni2 * 64 + bi * 16 + l15;
#pragma unroll
            for (int r = 0; r < 4; ++r) {
                int f = mi2 * 64 + ai * 16 + quad * 4 + r;
                Gb[(size_t)f * C_ + c] = f2bf(acc[ai][bi][r]);
            }
        }
}

// ---- MFMA: tT[b][e][f] += G @ wmT (atomic f32) ----
// XCD-pinned: blockIdx&7 == b, so G_b (3.2MB, 4x ei-reuse) is served from
// one XCD's L2 and the tT_b atomics stay XCD-local.
__global__ void k_gemm2(const u16* __restrict__ G, float* __restrict__ ws) {
    int b = blockIdx.x & 7;
    int blk = blockIdx.x >> 3;          // 56 = 7kg x 4ei x 2fi
    int kg = blk % 7; blk /= 7;
    int ei = blk % 4; int fi = blk / 4;
    int tid = threadIdx.x;
    int wave = tid >> 6, lane = tid & 63, quad = lane >> 4, l15 = lane & 15;
    int fbase = fi * 64 + wave * 16;
    int ebase = ei * 64;
    const u16* wmt = (const u16*)&ws[OFF_WMT];
    const u16* Gb = G + (size_t)b * KK_ * F_ * C_;
    v4f acc[4];
#pragma unroll
    for (int i = 0; i < 4; ++i) acc[i] = (v4f){0.f, 0.f, 0.f, 0.f};
    for (int kk = kg * 7; kk < kg * 7 + 7; ++kk) {
        const u16* Ga = Gb + ((size_t)kk * F_ + fbase + l15) * C_;
        const u16* Wb = wmt + ((size_t)kk * E_ + ebase + l15) * C_;
#pragma unroll 2
        for (int cs = 0; cs < 8; ++cs) {
            v8s af = *(const v8s*)(Ga + cs * 32 + quad * 8);
#pragma unroll
            for (int nt = 0; nt < 4; ++nt) {
                v8s bf = *(const v8s*)(Wb + (size_t)nt * 16 * C_ + cs * 32 + quad * 8);
                acc[nt] = __builtin_amdgcn_mfma_f32_16x16x32_bf16(af, bf, acc[nt], 0, 0, 0);
            }
        }
    }
#pragma unroll
    for (int nt = 0; nt < 4; ++nt)
#pragma unroll
        for (int r = 0; r < 4; ++r) {
            int e = ebase + nt * 16 + l15;
            int f = fbase + quad * 4 + r;
            atomicAdd(&ws[OFF_T + ((size_t)(b * E_ + e)) * F_ + f], acc[nt][r]);
        }
}

// ---- tT16[b][e][f] = bf16( a[b,f] * (tT + sphi[b,f]*b_m[e]) ) ---- (XCD-pinned)
__global__ void k_tfix(const float* __restrict__ b_m, float* __restrict__ ws) {
    int b = blockIdx.x & 7, e = blockIdx.x >> 3, f = threadIdx.x;
    float av = ws[OFF_A + b * F_ + f];
    float sp = ws[OFF_SPHI + b * F_ + f];
    float t = av * (ws[OFF_T + ((size_t)(b * E_ + e)) * F_ + f] + sp * b_m[e]);
    ((u16*)&ws[OFF_TT16])[((size_t)(b * E_ + e)) * F_ + f] = f2bf(t);
}

// ---- MFMA: hmS16[v][e] = bf16(rsD[v]*|phi@t|), csum partials (NO atomics) ----
// XCD-pinned: blockIdx&7 == b -> tt_b (64KB, re-read by 64 blocks) and
// phiT_b stay on one XCD's L2.
__global__ void k_hd(float* __restrict__ ws) {
    __shared__ u16 phiL[64 * 136];
    __shared__ float cspart[4][E_];       // per-wave column-sum partials
    int b = blockIdx.x & 7;
    int chunkIdx = blockIdx.x >> 3;
    int v0 = chunkIdx * 64;
    int tid = threadIdx.x;
    // stage phi[v][f] from phiT[f][v]
    {
        int f = tid & 127, seg = (tid >> 7) * 32;
        const u16* src = (const u16*)&ws[OFF_PHIT] + ((size_t)(b * F_ + f)) * V_ + v0 + seg;
        uint4 q0 = *(const uint4*)(src);
        uint4 q1 = *(const uint4*)(src + 8);
        uint4 q2 = *(const uint4*)(src + 16);
        uint4 q3 = *(const uint4*)(src + 24);
        u32 dw[16] = {q0.x, q0.y, q0.z, q0.w, q1.x, q1.y, q1.z, q1.w,
                      q2.x, q2.y, q2.z, q2.w, q3.x, q3.y, q3.z, q3.w};
#pragma unroll
        for (int j = 0; j < 16; ++j) {
            phiL[(seg + 2 * j) * 136 + f]     = (u16)(dw[j] & 0xffff);
            phiL[(seg + 2 * j + 1) * 136 + f] = (u16)(dw[j] >> 16);
        }
    }
    __syncthreads();
    int wave = tid >> 6, lane = tid & 63, quad = lane >> 4, l15 = lane & 15;
    const u16* tt = (const u16*)&ws[OFF_TT16] + (size_t)b * E_ * F_;
    v4f acc[16];
#pragma unroll
    for (int i = 0; i < 16; ++i) acc[i] = (v4f){0.f, 0.f, 0.f, 0.f};
#pragma unroll
    for (int kc = 0; kc < 4; ++kc) {
        v8s af = *(const v8s*)&phiL[(wave * 16 + l15) * 136 + kc * 32 + quad * 8];
#pragma unroll
        for (int nt = 0; nt < 16; ++nt) {
            v8s bf = *(const v8s*)(tt + (size_t)(nt * 16 + l15) * F_ + kc * 32 + quad * 8);
            acc[nt] = __builtin_amdgcn_mfma_f32_16x16x32_bf16(af, bf, acc[nt], 0, 0, 0);
        }
    }
#pragma unroll
    for (int nt = 0; nt < 16; ++nt)
#pragma unroll
        for (int r = 0; r < 4; ++r) acc[nt][r] = fabsf(acc[nt][r]);
    // row sums over e (256) -> rsD
    v4f rs = acc[0];
#pragma unroll
    for (int nt = 1; nt < 16; ++nt) rs += acc[nt];
#pragma unroll
    for (int m = 1; m < 16; m <<= 1) {
#pragma unroll
        for (int r = 0; r < 4; ++r) rs[r] += __shfl_xor(rs[r], m, 64);
    }
    float rsd[4];
#pragma unroll
    for (int r = 0; r < 4; ++r) rsd[r] = rsqrtf(rs[r]);
    // col sums (unscaled): quad-reduce in-wave -> per-wave LDS partial
#pragma unroll
    for (int nt = 0; nt < 16; ++nt) {
        float cs = acc[nt][0] + acc[nt][1] + acc[nt][2] + acc[nt][3];
        cs += __shfl_xor(cs, 16, 64);
        cs += __shfl_xor(cs, 32, 64);
        if (quad == 0) cspart[wave][nt * 16 + l15] = cs;
    }
    // store hmS16 = rsD*H
    u16* hm = (u16*)&ws[OFF_XPT];
#pragma unroll
    for (int nt = 0; nt < 16; ++nt)
#pragma unroll
        for (int r = 0; r < 4; ++r) {
            int v = v0 + wave * 16 + quad * 4 + r;
            hm[((size_t)(b * V_ + v)) * E_ + nt * 16 + l15] = f2bf(acc[nt][r] * rsd[r]);
        }
    __syncthreads();
    // cross-wave reduce + one coalesced plain store per thread
    {
        int e = tid;
        float s = cspart[0][e] + cspart[1][e] + cspart[2][e] + cspart[3][e];
        ws[OFF_T + ((size_t)(b * 64 + chunkIdx)) * E_ + e] = s;
    }
}

// ---- csum[b][e] = sum_chunk csp[b][chunk][e] ----
__global__ void k_csum(float* __restrict__ ws) {
    int b = blockIdx.x, e = threadIdx.x;
    const float* p = &ws[OFF_T + (size_t)b * 64 * E_ + e];
    float s = 0.f;
    for (int i = 0; i < 64; ++i) s += p[(size_t)i * E_];
    ws[OFF_CSUM + b * E_ + e] = s;
}

// ---- MFMA: tmp partials[vs][b][c][e] = sum_{v in slice} xT[c][v]*hmS^T[e][v] ----
// NO atomics; XCD-pinned by b (hm_b and x_b stay L2-local).
__global__ __launch_bounds__(512, 2) void k_tmp(const float* __restrict__ x,
                                                float* __restrict__ ws,
                                                float* __restrict__ part) {
    __shared__ u16 xT[256 * 40];
    __shared__ u16 hT[128 * 40];
    int b = blockIdx.x & 7;
    int blk = blockIdx.x >> 3;          // 32 = 2eh x 16vs
    int eh = blk & 1;
    int vs = blk >> 1;
    int v0b = vs * 256;
    int tid = threadIdx.x;
    int wave = tid >> 6, lane = tid & 63, quad = lane >> 4, l15 = lane & 15;
    int m0 = wave * 32;
    const u16* hmS = (const u16*)&ws[OFF_XPT];
    v4f acc[2][8];
#pragma unroll
    for (int i = 0; i < 2; ++i)
#pragma unroll
        for (int j = 0; j < 8; ++j) acc[i][j] = (v4f){0.f, 0.f, 0.f, 0.f};
    int sv = tid & 31, sg = tid >> 5;   // staging roles
#pragma unroll 1
    for (int ch = 0; ch < 8; ++ch) {
        int vbase = v0b + ch * 32;
        // load x row (16 f32) and hm row (8 u16) into regs
        const float* xr = x + ((size_t)(b * V_ + vbase + sv)) * C_ + sg * 16;
        float4 xf0 = *(const float4*)(xr);
        float4 xf1 = *(const float4*)(xr + 4);
        float4 xf2 = *(const float4*)(xr + 8);
        float4 xf3 = *(const float4*)(xr + 12);
        const u16* hr = hmS + ((size_t)(b * V_ + vbase + sv)) * E_ + eh * 128 + sg * 8;
        uint4 hq = *(const uint4*)hr;
        u16 hp[8] = {(u16)(hq.x & 0xffff), (u16)(hq.x >> 16), (u16)(hq.y & 0xffff),
                     (u16)(hq.y >> 16), (u16)(hq.z & 0xffff), (u16)(hq.z >> 16),
                     (u16)(hq.w & 0xffff), (u16)(hq.w >> 16)};
        float xv[16] = {xf0.x, xf0.y, xf0.z, xf0.w, xf1.x, xf1.y, xf1.z, xf1.w,
                        xf2.x, xf2.y, xf2.z, xf2.w, xf3.x, xf3.y, xf3.z, xf3.w};
        __syncthreads();
#pragma unroll
        for (int i = 0; i < 16; ++i) xT[(sg * 16 + i) * 40 + sv] = f2bf(xv[i]);
#pragma unroll
        for (int i = 0; i < 8; ++i) hT[(sg * 8 + i) * 40 + sv] = hp[i];
        __syncthreads();
        v8s a0 = *(const v8s*)&xT[(m0 + l15) * 40 + quad * 8];
        v8s a1 = *(const v8s*)&xT[(m0 + 16 + l15) * 40 + quad * 8];
#pragma unroll
        for (int nt = 0; nt < 8; ++nt) {
            v8s bf = *(const v8s*)&hT[(nt * 16 + l15) * 40 + quad * 8];
            acc[0][nt] = __builtin_amdgcn_mfma_f32_16x16x32_bf16(a0, bf, acc[0][nt], 0, 0, 0);
            acc[1][nt] = __builtin_amdgcn_mfma_f32_16x16x32_bf16(a1, bf, acc[1][nt], 0, 0, 0);
        }
    }
    float* po = part + (size_t)vs * SLICE;
#pragma unroll
    for (int mt = 0; mt < 2; ++mt)
#pragma unroll
        for (int nt = 0; nt < 8; ++nt)
#pragma unroll
            for (int r = 0; r < 4; ++r) {
                int c = m0 + mt * 16 + quad * 4 + r;
                int e = eh * 128 + nt * 16 + l15;
                po[((size_t)(b * C_ + c)) * E_ + e] = acc[mt][nt][r];
            }
}

// ---- tmp2T16[c][e] = bf16( (sum_s part[s][c][e]) / csum[e] ) ---- (XCD-pinned)
__global__ void k_t2fix(const float* __restrict__ part, float* __restrict__ ws) {
    int b = blockIdx.x & 7, c = blockIdx.x >> 3, e = threadIdx.x;
    float binv = 1.0f / ws[OFF_CSUM + b * E_ + e];
    size_t idx = ((size_t)(b * C_ + c)) * E_ + e;
    float tv = 0.f;
#pragma unroll
    for (int s = 0; s < 16; ++s) tv += part[(size_t)s * SLICE + idx];
    ((u16*)&ws[OFF_T2T16])[idx] = f2bf(tv * binv);
}

// ---- MFMA fused: out = (x - hmS16 @ tmp2T16) @ W2 + b2 ----
// XCD-pinned: blockIdx&7 == b -> t2_b (128KB, re-read by 64 blocks) L2-local.
__global__ __launch_bounds__(256, 2) void k_out(const float* __restrict__ x,
                                                const float* __restrict__ b2,
                                                const float* __restrict__ ws,
                                                float* __restrict__ io) {
    __shared__ u16 dL[64 * 264];
    int b = blockIdx.x & 7;
    int v0 = (blockIdx.x >> 3) * 64;
    int tid = threadIdx.x;
    int wave = tid >> 6, lane = tid & 63, quad = lane >> 4, l15 = lane & 15;
    const u16* hm = (const u16*)&ws[OFF_XPT] + ((size_t)(b * V_ + v0 + wave * 16 + l15)) * E_;
    const u16* t2 = (const u16*)&ws[OFF_T2T16] + (size_t)b * C_ * E_;
    v4f acc[16];
#pragma unroll
    for (int i = 0; i < 16; ++i) acc[i] = (v4f){0.f, 0.f, 0.f, 0.f};
#pragma unroll 2
    for (int kc = 0; kc < 8; ++kc) {
        v8s af = *(const v8s*)(hm + kc * 32 + quad * 8);
#pragma unroll
        for (int nt = 0; nt < 16; ++nt) {
            v8s bf = *(const v8s*)(t2 + (size_t)(nt * 16 + l15) * E_ + kc * 32 + quad * 8);
            acc[nt] = __builtin_amdgcn_mfma_f32_16x16x32_bf16(af, bf, acc[nt], 0, 0, 0);
        }
    }
#pragma unroll
    for (int nt = 0; nt < 16; ++nt)
#pragma unroll
        for (int r = 0; r < 4; ++r) {
            int v = wave * 16 + quad * 4 + r;
            int c = nt * 16 + l15;
            float xv = x[((size_t)(b * V_ + v0 + v)) * C_ + c];
            dL[v * 264 + c] = f2bf(xv - acc[nt][r]);
        }
    __syncthreads();
    const u16* w2t = (const u16*)&ws[OFF_W2T16];
    v4f acc2[16];
#pragma unroll
    for (int i = 0; i < 16; ++i) acc2[i] = (v4f){0.f, 0.f, 0.f, 0.f};
#pragma unroll 2
    for (int kc = 0; kc < 8; ++kc) {
        v8s af = *(const v8s*)&dL[(wave * 16 + l15) * 264 + kc * 32 + quad * 8];
#pragma unroll
        for (int nt = 0; nt < 16; ++nt) {
            v8s bf = *(const v8s*)(w2t + (size_t)(nt * 16 + l15) * C_ + kc * 32 + quad * 8);
            acc2[nt] = __builtin_amdgcn_mfma_f32_16x16x32_bf16(af, bf, acc2[nt], 0, 0, 0);
        }
    }
#pragma unroll
    for (int nt = 0; nt < 16; ++nt)
#pragma unroll
        for (int r = 0; r < 4; ++r) {
            int v = wave * 16 + quad * 4 + r;
            int co = nt * 16 + l15;
            io[((size_t)(b * V_ + v0 + v)) * C_ + co] = acc2[nt][r] + b2[co];
        }
}

extern "C" void kernel_launch(void* const* d_in, const int* in_sizes, int n_in,
                              void* d_out, int out_size, void* d_ws, size_t ws_size,
                              hipStream_t stream) {
    const float* x     = (const float*)d_in[0];
    const float* w_phi = (const float*)d_in[1];
    const float* b_phi = (const float*)d_in[2];
    const float* w_a   = (const float*)d_in[3];
    const float* b_a   = (const float*)d_in[4];
    const float* w_m   = (const float*)d_in[5];
    const float* b_m   = (const float*)d_in[6];
    const float* w2    = (const float*)d_in[7];
    const float* b2    = (const float*)d_in[8];
    float* ws = (float*)d_ws;
    float* io = (float*)d_out;

    hipMemsetAsync(ws, 0, ZERO_HEAD * sizeof(float), stream);
    hipMemsetAsync(ws + OFF_XPT, 0, XPT_FLOATS * sizeof(float), stream);
    k_xsum<<<dim3(256), dim3(256), 0, stream>>>(x, ws);
    k_a<<<dim3(8), dim3(128), 0, stream>>>(w_a, b_a, ws);
    k_phi<<<dim3(4096), dim3(128), 0, stream>>>(x, w_phi, b_phi, ws);
    k_padx<<<dim3(512), dim3(256), 0, stream>>>(x, ws);
    k_wmt<<<dim3(49), dim3(256), 0, stream>>>(w_m, ws);
    k_w2t<<<dim3(256), dim3(256), 0, stream>>>(w2, ws);
    k_gemm1<<<dim3(392), dim3(512), 0, stream>>>(ws, (u16*)d_out);
    k_gemm2<<<dim3(448), dim3(256), 0, stream>>>((const u16*)d_out, ws);
    k_tfix<<<dim3(2048), dim3(128), 0, stream>>>(b_m, ws);
    k_hd<<<dim3(512), dim3(256), 0, stream>>>(ws);
    k_csum<<<dim3(8), dim3(256), 0, stream>>>(ws);
    k_tmp<<<dim3(256), dim3(512), 0, stream>>>(x, ws, (float*)d_out);
    k_t2fix<<<dim3(2048), dim3(256), 0, stream>>>((const float*)d_out, ws);
    k_out<<<dim3(512), dim3(256), 0, stream>>>(x, b2, ws, io);
}